// Round 2
// baseline (249.131 us; speedup 1.0000x reference)
//
#include <hip/hip_runtime.h>

// FCOS post-processing: scores = sqrt(sig(cls)*sig(cent)); top-100 of 21M;
// gather (faithful flat[pt_idx] quirk); box decode; greedy NMS (K=100, IoU>0.5).
//
// ws layout: [0..15] header {cand_count, rescan_flag, T_bin, arrival}
//            [16..4111] hist[1024] (scores in [0.80,1.0), bin width 1/5120)
//            [4352 ...] cand_score[cap] ; cand_idx[cap]

#define NPTS 262144
#define NCLS 80
#define NFLAT (NPTS * NCLS)      // 20,971,520
#define NF4 (NFLAT / 4)          // 5,242,880
#define KDET 100
#define HB 1024
#define HIST_LO 0.80f
#define HIST_SCALE 5120.0f       // HB / 0.2
#define BINW (1.0f / HIST_SCALE)
#define THETA0 0.90f
#define MCAP 512
#define SBUF 512                 // per-block candidate staging
#define NB1 1024
#define NT1 256

__device__ __forceinline__ float sigm(float x) {
    // fast sigmoid: 1/(1+exp(-x)); self-consistent across kernels (bit-exact)
    return __builtin_amdgcn_rcpf(1.0f + __expf(-x));
}

// ------ Pass 1: scores -> histogram + candidates; last block picks threshold --
__global__ __launch_bounds__(NT1) void k_score_hist(
    const float* __restrict__ cls, const float* __restrict__ cent,
    unsigned* __restrict__ hist, unsigned* __restrict__ hdr,
    float* __restrict__ cscore, unsigned* __restrict__ cidx, int cap)
{
    __shared__ unsigned sh[HB];
    __shared__ float    sbs[SBUF];
    __shared__ unsigned sbi[SBUF];
    __shared__ unsigned sbn, sbase, sbm;
    __shared__ int      lastblk;
    for (int i = threadIdx.x; i < HB; i += NT1) sh[i] = 0;
    if (threadIdx.x == 0) sbn = 0;
    __syncthreads();

    const float4* c4 = (const float4*)cls;
    int tid = blockIdx.x * NT1 + threadIdx.x;
    #pragma unroll 2
    for (int it = 0; it < NF4 / (NB1 * NT1); ++it) {   // 20 iters, coalesced f4
        int g = tid + it * (NB1 * NT1);
        float4 v = c4[g];
        int p = g / 20;                                 // 20 float4 per point
        float sct = sigm(cent[p]);
        float sv[4] = {v.x, v.y, v.z, v.w};
        #pragma unroll
        for (int i = 0; i < 4; ++i) {
            float s = sqrtf(sigm(sv[i]) * sct);
            if (s >= HIST_LO) {
                int b = (int)((s - HIST_LO) * HIST_SCALE);
                if (b > HB - 1) b = HB - 1;
                atomicAdd(&sh[b], 1u);
                if (s >= THETA0) {
                    unsigned pos = atomicAdd(&sbn, 1u);
                    if (pos < SBUF) { sbs[pos] = s; sbi[pos] = (unsigned)(g * 4 + i); }
                    else {                               // staging overflow: direct
                        unsigned q = atomicAdd(&hdr[0], 1u);
                        if (q < (unsigned)cap) { cscore[q] = s; cidx[q] = (unsigned)(g * 4 + i); }
                    }
                }
            }
        }
    }
    __syncthreads();
    // merge histogram + flush candidate staging (1 counter atomic per block)
    for (int i = threadIdx.x; i < HB; i += NT1) {
        unsigned c = sh[i];
        if (c) atomicAdd(&hist[i], c);
    }
    if (threadIdx.x == 0) {
        unsigned m = sbn < SBUF ? sbn : SBUF;
        sbm = m;
        sbase = m ? atomicAdd(&hdr[0], m) : 0u;
    }
    __syncthreads();
    for (unsigned i = threadIdx.x; i < sbm; i += NT1) {
        unsigned q = sbase + i;
        if (q < (unsigned)cap) { cscore[q] = sbs[i]; cidx[q] = sbi[i]; }
    }
    // arrival; last block computes the exact top-100 threshold bin
    __syncthreads();
    if (threadIdx.x == 0) {
        __threadfence();
        lastblk = (atomicAdd(&hdr[3], 1u) == NB1 - 1);
    }
    __syncthreads();
    if (!lastblk) return;
    __threadfence();
    for (int i = threadIdx.x; i < HB; i += NT1)
        sh[i] = __hip_atomic_load(&hist[i], __ATOMIC_RELAXED, __HIP_MEMORY_SCOPE_AGENT);
    __syncthreads();
    if (threadIdx.x == 0) {
        unsigned cum = 0; int T = -1;
        for (int b = HB - 1; b >= 0; --b) { cum += sh[b]; if (cum >= KDET) { T = b; break; } }
        unsigned cand = __hip_atomic_load(&hdr[0], __ATOMIC_RELAXED, __HIP_MEMORY_SCOPE_AGENT);
        int rescan;
        if (T < 0) { T = 0; rescan = 1; }               // <100 scores >= 0.80 (never)
        else {
            float edge = HIST_LO + (float)T * BINW;     // bin-T lower edge
            rescan = (edge < THETA0 + 2.0f * BINW) || (cand > (unsigned)cap);
        }
        ((int*)hdr)[2] = T;
        if (rescan) hdr[0] = 0;                          // reset for k_rescan
        __threadfence();
        hdr[1] = (unsigned)rescan;
    }
}

// ------ Pass 2 (fallback, early-exit): collect all with bin >= T --------------
__global__ __launch_bounds__(NT1) void k_rescan(
    const float* __restrict__ cls, const float* __restrict__ cent,
    unsigned* __restrict__ hdr, float* __restrict__ cscore,
    unsigned* __restrict__ cidx, int cap)
{
    if (hdr[1] == 0) return;
    int T = ((int*)hdr)[2];
    const float4* c4 = (const float4*)cls;
    int tid = blockIdx.x * NT1 + threadIdx.x;
    #pragma unroll 1
    for (int it = 0; it < NF4 / (NB1 * NT1); ++it) {
        int g = tid + it * (NB1 * NT1);
        float4 v = c4[g];
        int p = g / 20;
        float sct = sigm(cent[p]);
        float sv[4] = {v.x, v.y, v.z, v.w};
        #pragma unroll
        for (int i = 0; i < 4; ++i) {
            float s = sqrtf(sigm(sv[i]) * sct);
            if (s >= HIST_LO) {
                int b = (int)((s - HIST_LO) * HIST_SCALE);
                if (b > HB - 1) b = HB - 1;
                if (b >= T) {
                    unsigned pos = atomicAdd(&hdr[0], 1u);
                    if (pos < (unsigned)cap) { cscore[pos] = s; cidx[pos] = (unsigned)(g * 4 + i); }
                }
            }
        }
    }
}

// ------ Pass 3: exact top-100, gather/decode, stable sort, NMS, outputs -------
__global__ __launch_bounds__(256) void k_finalize(
    const float* __restrict__ cls, const float* __restrict__ cent,
    const float* __restrict__ boxp, const float* __restrict__ pts,
    const float* __restrict__ strd,
    const unsigned* __restrict__ hdr, const float* __restrict__ cscore,
    const unsigned* __restrict__ cidx, int cap, float* __restrict__ out)
{
    __shared__ float ss[MCAP];
    __shared__ unsigned si[MCAP];
    __shared__ unsigned mcnt;
    __shared__ float ioum[KDET * KDET];
    __shared__ float sel_s[KDET];
    __shared__ int   sel_c[KDET];
    __shared__ float sel_b[KDET][4];
    __shared__ int   ordv[KDET];
    __shared__ unsigned char keepA[KDET];
    __shared__ float bs[KDET][4];
    __shared__ float sso[KDET];
    __shared__ int   cso[KDET];

    int T = ((const int*)hdr)[2];
    unsigned n = hdr[0]; if (n > (unsigned)cap) n = (unsigned)cap;
    if (threadIdx.x == 0) mcnt = 0;
    __syncthreads();

    // filter candidates to bin >= T (expected ~100-200)
    for (unsigned i = threadIdx.x; i < n; i += 256) {
        float s = cscore[i];
        int b = (int)((s - HIST_LO) * HIST_SCALE);
        if (b > HB - 1) b = HB - 1;
        if (b >= T) {
            unsigned p = atomicAdd(&mcnt, 1u);
            if (p < MCAP) { ss[p] = s; si[p] = cidx[i]; }
        }
    }
    __syncthreads();
    unsigned M = mcnt < MCAP ? mcnt : MCAP;
    for (unsigned i = threadIdx.x; i < MCAP; i += 256)
        if (i >= M) { ss[i] = -1.0f; si[i] = 0xFFFFFFFFu; }
    __syncthreads();

    // bitonic sort MCAP: (score desc, idx asc) == lax.top_k tie order
    for (int k2 = 2; k2 <= MCAP; k2 <<= 1) {
        for (int j = k2 >> 1; j > 0; j >>= 1) {
            for (int t = threadIdx.x; t < MCAP; t += 256) {
                int x = t ^ j;
                if (x > t) {
                    float s1 = ss[t], s2 = ss[x];
                    unsigned i1 = si[t], i2 = si[x];
                    bool rank21 = (s2 > s1) || (s2 == s1 && i2 < i1);
                    bool rank12 = (s1 > s2) || (s1 == s2 && i1 < i2);
                    bool doSwap = ((t & k2) == 0) ? rank21 : rank12;
                    if (doSwap) { ss[t] = s2; ss[x] = s1; si[t] = i2; si[x] = i1; }
                }
            }
            __syncthreads();
        }
    }

    // gather + decode (faithful quirk: score gathered at flat[pt_idx])
    if (threadIdx.x < KDET) {
        int k = threadIdx.x;
        unsigned j = si[k];
        if (ss[k] < 0.0f) j = 0;          // defensive
        unsigned pt = j / (unsigned)NCLS;
        sel_c[k] = (int)(j % (unsigned)NCLS);
        sel_s[k] = sqrtf(sigm(cls[pt]) * sigm(cent[pt / (unsigned)NCLS]));
        float l = boxp[pt * 4 + 0], tt = boxp[pt * 4 + 1];
        float r = boxp[pt * 4 + 2], bb = boxp[pt * 4 + 3];
        float st = strd[pt];
        float px = pts[pt * 2 + 0], py = pts[pt * 2 + 1];
        sel_b[k][0] = __fsub_rn(px, __fmul_rn(l,  st));
        sel_b[k][1] = __fsub_rn(py, __fmul_rn(tt, st));
        sel_b[k][2] = __fadd_rn(px, __fmul_rn(r,  st));
        sel_b[k][3] = __fadd_rn(py, __fmul_rn(bb, st));
    }
    __syncthreads();

    // stable argsort(-sel_s): ties -> lower k first (jnp.argsort is stable)
    if (threadIdx.x < KDET) {
        int k = threadIdx.x; float sk = sel_s[k]; int rank = 0;
        for (int j = 0; j < KDET; ++j) {
            float sj = sel_s[j];
            if (sj > sk || (sj == sk && j < k)) ++rank;
        }
        ordv[rank] = k;
    }
    __syncthreads();
    if (threadIdx.x < KDET) {
        int i = threadIdx.x, o = ordv[i];
        sso[i] = sel_s[o]; cso[i] = sel_c[o];
        bs[i][0] = sel_b[o][0]; bs[i][1] = sel_b[o][1];
        bs[i][2] = sel_b[o][2]; bs[i][3] = sel_b[o][3];
        keepA[i] = 1;
    }
    __syncthreads();

    // pairwise IoU (exact reference formula)
    for (int t = threadIdx.x; t < KDET * KDET; t += 256) {
        int i = t / KDET, j = t % KDET;
        float ax1 = bs[i][0], ay1 = bs[i][1], ax2 = bs[i][2], ay2 = bs[i][3];
        float bx1 = bs[j][0], by1 = bs[j][1], bx2 = bs[j][2], by2 = bs[j][3];
        float areaA = (ax2 - ax1) * (ay2 - ay1);
        float areaB = (bx2 - bx1) * (by2 - by1);
        float lx = fmaxf(ax1, bx1), ly = fmaxf(ay1, by1);
        float rx = fminf(ax2, bx2), ry = fminf(ay2, by2);
        float w = fmaxf(rx - lx, 0.0f), h = fmaxf(ry - ly, 0.0f);
        float inter = w * h;
        ioum[t] = inter / (areaA + areaB - inter + 1e-9f);
    }
    __syncthreads();

    // greedy NMS: serial over i, parallel suppression over j
    for (int i = 0; i < KDET; ++i) {
        if (keepA[i]) {
            int j = threadIdx.x;
            if (j > i && j < KDET && ioum[i * KDET + j] > 0.5f) keepA[j] = 0;
        }
        __syncthreads();
    }

    // outputs: boxes [100,4] | scores [100] | classes [100] (float, -1 suppressed)
    if (threadIdx.x < KDET) {
        int i = threadIdx.x;
        bool kp = keepA[i] != 0;
        out[i * 4 + 0] = kp ? bs[i][0] : 0.0f;
        out[i * 4 + 1] = kp ? bs[i][1] : 0.0f;
        out[i * 4 + 2] = kp ? bs[i][2] : 0.0f;
        out[i * 4 + 3] = kp ? bs[i][3] : 0.0f;
        out[4 * KDET + i] = kp ? sso[i] : 0.0f;
        out[5 * KDET + i] = kp ? (float)cso[i] : -1.0f;
    }
}

extern "C" void kernel_launch(void* const* d_in, const int* in_sizes, int n_in,
                              void* d_out, int out_size, void* d_ws, size_t ws_size,
                              hipStream_t stream)
{
    const float* cls  = (const float*)d_in[0];
    const float* boxp = (const float*)d_in[1];
    const float* cent = (const float*)d_in[2];
    const float* pts  = (const float*)d_in[3];
    const float* strd = (const float*)d_in[4];
    float* out = (float*)d_out;

    char* ws = (char*)d_ws;
    unsigned* hdr  = (unsigned*)ws;
    unsigned* hist = (unsigned*)(ws + 16);
    size_t capS = ws_size > 4360 ? (ws_size - 4352) / 8 : 64;
    int cap = (int)(capS > 32768 ? 32768 : capS);
    float*    cscore = (float*)(ws + 4352);
    unsigned* cidx   = (unsigned*)(ws + 4352 + (size_t)cap * 4);

    hipMemsetAsync(d_ws, 0, 4112, stream);  // header + hist
    hipLaunchKernelGGL(k_score_hist, dim3(NB1), dim3(NT1), 0, stream,
                       cls, cent, hist, hdr, cscore, cidx, cap);
    hipLaunchKernelGGL(k_rescan, dim3(NB1), dim3(NT1), 0, stream,
                       cls, cent, hdr, cscore, cidx, cap);
    hipLaunchKernelGGL(k_finalize, dim3(1), dim3(256), 0, stream,
                       cls, cent, boxp, pts, strd, hdr, cscore, cidx, cap, out);
}